// Round 10
// baseline (570.717 us; speedup 1.0000x reference)
//
#include <hip/hip_runtime.h>
#include <hip/hip_bf16.h>

#define E_EDGES 500000
#define NN 50000

typedef unsigned short u16;
typedef __attribute__((ext_vector_type(8))) short s16x8;
typedef __attribute__((ext_vector_type(4))) float f32x4;

__device__ __forceinline__ short f2bf(float f) {
    unsigned u = __builtin_bit_cast(unsigned, f);
    u += 0x7fffu + ((u >> 16) & 1u);
    return (short)(u >> 16);
}

__device__ __forceinline__ float lrelu(float x) { return x > 0.0f ? x : 0.01f * x; }

__device__ __forceinline__ s16x8 cvt8(float4 lo, float4 hi) {
    s16x8 w;
    w[0] = f2bf(lo.x); w[1] = f2bf(lo.y); w[2] = f2bf(lo.z); w[3] = f2bf(lo.w);
    w[4] = f2bf(hi.x); w[5] = f2bf(hi.y); w[6] = f2bf(hi.z); w[7] = f2bf(hi.w);
    return w;
}

// ---- weight prep: WT[g][n][k] = bf16(W_g[k][n]), g in {src, tgt, edge} ----
__global__ void kprep(const float* __restrict__ Wsrc, const float* __restrict__ Wtgt,
                      const float* __restrict__ Wedge, u16* __restrict__ WT) {
    int i = blockIdx.x * 256 + threadIdx.x;
    if (i >= 3 * 16384) return;
    int g = i >> 14, nk = i & 16383, n = nk >> 7, k = nk & 127;
    const float* W = (g == 0) ? Wsrc : (g == 1) ? Wtgt : Wedge;
    WT[i] = (u16)f2bf(W[k * 128 + n]);
}

// ---- K1: one-sync design. M=64 tile, stage send+recv+eattr together
// (12 chunk-pairs/thread, 2 batches of 6), single __syncthreads, then
// q = s@Ws + r@Wt + e@We in one accumulator; B frags direct from L2.
// LDS 52.2 KB -> 3 blocks/CU = 12 waves/CU. ----
__global__ __launch_bounds__(256, 2) void k1(
    const float* __restrict__ recv, const float* __restrict__ send,
    const float* __restrict__ eattr, const int* __restrict__ sidx,
    const u16* __restrict__ WT, const float* __restrict__ attn,
    float* __restrict__ ez, float* __restrict__ denom)
{
    __shared__ u16 lds[3][64][136];   // 52224 B
    const int tid = threadIdx.x;
    const int lane = tid & 63, wv = tid >> 6;        // 4 waves, 16 rows each
    const int l15 = lane & 15, lg = (lane >> 4) & 3;
    const int row0 = blockIdx.x * 64;

    const float* Xg[3] = {send, recv, eattr};

    // stage: 3 mats x 64 rows x 16 granules = 3072 chunks of 32B, 12/thread
    float4 ra[6][2];
#pragma unroll
    for (int half = 0; half < 2; ++half) {
#pragma unroll
        for (int q = 0; q < 6; ++q) {
            int c = tid + 256 * (q + 6 * half);
            int mat = c >> 10, rem = c & 1023;
            int row = rem >> 4, p = rem & 15;
            const float* src = Xg[mat] + (size_t)min(row0 + row, E_EDGES - 1) * 128 + p * 8;
            ra[q][0] = *(const float4*)src;
            ra[q][1] = *(const float4*)(src + 4);
        }
#pragma unroll
        for (int q = 0; q < 6; ++q) {
            int c = tid + 256 * (q + 6 * half);
            int mat = c >> 10, rem = c & 1023;
            *(s16x8*)&lds[mat][rem >> 4][(rem & 15) * 8] = cvt8(ra[q][0], ra[q][1]);
        }
    }
    __syncthreads();

    f32x4 acc[8];
#pragma unroll
    for (int n = 0; n < 8; ++n) acc[n] = (f32x4){0.f, 0.f, 0.f, 0.f};

#pragma unroll
    for (int g = 0; g < 3; ++g) {
        const u16* Bg = WT + g * 16384;
#pragma unroll
        for (int kk = 0; kk < 4; ++kk) {
            int k0 = kk * 32 + lg * 8;
            s16x8 a = *(const s16x8*)&lds[g][wv * 16 + l15][k0];
#pragma unroll
            for (int n = 0; n < 8; ++n) {
                s16x8 b = *(const s16x8*)(Bg + (n * 16 + l15) * 128 + k0);
                acc[n] = __builtin_amdgcn_mfma_f32_16x16x32_bf16(a, b, acc[n], 0, 0, 0);
            }
        }
    }

    float av[8];
#pragma unroll
    for (int n = 0; n < 8; ++n) av[n] = attn[n * 16 + l15];

#pragma unroll
    for (int h = 0; h < 4; ++h) {
        float part[4];
#pragma unroll
        for (int j = 0; j < 4; ++j)
            part[j] = lrelu(acc[2 * h][j]) * av[2 * h] +
                      lrelu(acc[2 * h + 1][j]) * av[2 * h + 1];
#pragma unroll
        for (int off = 1; off < 16; off <<= 1) {
#pragma unroll
            for (int j = 0; j < 4; ++j) part[j] += __shfl_xor(part[j], off, 64);
        }
        if (l15 == h) {
#pragma unroll
            for (int j = 0; j < 4; ++j) {
                int r = row0 + wv * 16 + lg * 4 + j;
                if (r < E_EDGES) {
                    float ezv = __expf(part[j]);
                    ez[(size_t)r * 4 + h] = ezv;
                    atomicAdd(&denom[(size_t)sidx[r] * 4 + h], ezv);
                }
            }
        }
    }
}

// ---- K2: R9 proven structure (ldsA+ldsB, one sync), a = ez/denom fused ----
__global__ __launch_bounds__(256, 2) void k2(
    const float* __restrict__ recv, const int* __restrict__ ridx,
    const int* __restrict__ sidx, const u16* __restrict__ WTt,
    const float* __restrict__ ez, const float* __restrict__ denom,
    float* __restrict__ out0, float* __restrict__ out1)
{
    __shared__ u16 ldsA[128][136];
    __shared__ u16 ldsB[128][136];
    int tid = threadIdx.x;
    int lane = tid & 63, wv = tid >> 6;
    int l15 = lane & 15, lg = lane >> 4;
    int blockRow = blockIdx.x * 128;

    f32x4 acc[2][8];
#pragma unroll
    for (int m = 0; m < 2; ++m)
#pragma unroll
        for (int n = 0; n < 8; ++n) acc[m][n] = (f32x4){0.f, 0.f, 0.f, 0.f};

#pragma unroll
    for (int it = 0; it < 8; ++it) {
        int chunk = it * 256 + tid;
        int row = chunk >> 4, kc = (chunk & 15) << 3;
        int ge = min(blockRow + row, E_EDGES - 1);
        const float* p = recv + (size_t)ge * 128 + kc;
        float4 v0 = *(const float4*)p;
        float4 v1 = *(const float4*)(p + 4);
        *(s16x8*)&ldsA[row][kc] = cvt8(v0, v1);
    }
#pragma unroll
    for (int it = 0; it < 8; ++it) {
        int chunk = it * 256 + tid;
        int n = chunk >> 4, kc = (chunk & 15) << 3;
        *(s16x8*)&ldsB[n][kc] = *(const s16x8*)(WTt + n * 128 + kc);
    }
    __syncthreads();

#pragma unroll
    for (int kk = 0; kk < 4; ++kk) {
        int k0 = kk * 32 + lg * 8;
        s16x8 a0 = *(const s16x8*)&ldsA[wv * 32 + l15][k0];
        s16x8 a1 = *(const s16x8*)&ldsA[wv * 32 + 16 + l15][k0];
#pragma unroll
        for (int n = 0; n < 8; ++n) {
            s16x8 b = *(const s16x8*)&ldsB[n * 16 + l15][k0];
            acc[0][n] = __builtin_amdgcn_mfma_f32_16x16x32_bf16(a0, b, acc[0][n], 0, 0, 0);
            acc[1][n] = __builtin_amdgcn_mfma_f32_16x16x32_bf16(a1, b, acc[1][n], 0, 0, 0);
        }
    }

#pragma unroll
    for (int m = 0; m < 2; ++m) {
#pragma unroll
        for (int j = 0; j < 4; ++j) {
            int r = blockRow + wv * 32 + m * 16 + lg * 4 + j;
            if (r < E_EDGES) {
                int s = sidx[r];
                float4 ezv = *(const float4*)(ez + (size_t)r * 4);
                float4 dn = *(const float4*)(denom + (size_t)s * 4);
                float a0 = ezv.x / dn.x, a1 = ezv.y / dn.y;
                float a2 = ezv.z / dn.z, a3 = ezv.w / dn.w;
                float lo = 0.25f * (acc[m][0][j] * a0 + acc[m][2][j] * a1 +
                                    acc[m][4][j] * a2 + acc[m][6][j] * a3);
                float hi = 0.25f * (acc[m][1][j] * a0 + acc[m][3][j] * a1 +
                                    acc[m][5][j] * a2 + acc[m][7][j] * a3);
                out1[(size_t)r * 32 + l15] = lo;
                out1[(size_t)r * 32 + 16 + l15] = hi;
                int rv = ridx[r];
                atomicAdd(&out0[(size_t)rv * 32 + l15], lo);
                atomicAdd(&out0[(size_t)rv * 32 + 16 + l15], hi);
            }
        }
    }
}

extern "C" void kernel_launch(void* const* d_in, const int* in_sizes, int n_in,
                              void* d_out, int out_size, void* d_ws, size_t ws_size,
                              hipStream_t stream) {
    const float* recv  = (const float*)d_in[0];
    const float* send  = (const float*)d_in[1];
    const float* eattr = (const float*)d_in[2];
    const int*   sidx  = (const int*)d_in[3];
    const int*   ridx  = (const int*)d_in[4];
    const float* Wsrc  = (const float*)d_in[5];
    const float* Wtgt  = (const float*)d_in[6];
    const float* Wedge = (const float*)d_in[7];
    const float* attn  = (const float*)d_in[8];

    char* ws = (char*)d_ws;
    u16*   WT    = (u16*)ws;                         // 98304 B
    float* ez    = (float*)(ws + 131072);            // 8,000,000 B
    float* denom = (float*)(ws + 131072 + 8000000);  // 800,000 B

    float* out0 = (float*)d_out;                     // [N,32]
    float* out1 = out0 + (size_t)NN * 32;            // [E,32]

    hipMemsetAsync(denom, 0, (size_t)NN * 4 * sizeof(float), stream);
    hipMemsetAsync(out0, 0, (size_t)NN * 32 * sizeof(float), stream);

    kprep<<<192, 256, 0, stream>>>(Wsrc, Wtgt, Wedge, WT);

    int nb1 = (E_EDGES + 63) / 64;    // 7813
    int nb2 = (E_EDGES + 127) / 128;  // 3907
    k1<<<nb1, 256, 0, stream>>>(recv, send, eattr, sidx, WT, attn, ez, denom);
    k2<<<nb2, 256, 0, stream>>>(recv, ridx, sidx, WT + 16384, ez, denom, out0, out1);
}

// Round 11
// 305.181 us; speedup vs baseline: 1.8701x; 1.8701x over previous
//
#include <hip/hip_runtime.h>
#include <hip/hip_bf16.h>

#define E_EDGES 500000
#define NN 50000

typedef unsigned short u16;
typedef __attribute__((ext_vector_type(8))) short s16x8;
typedef __attribute__((ext_vector_type(4))) float f32x4;

#define BAR() __builtin_amdgcn_s_barrier()
#define SCHED0() __builtin_amdgcn_sched_barrier(0)
#define WAITLGKM0() asm volatile("s_waitcnt lgkmcnt(0)" ::: "memory")

__device__ __forceinline__ short f2bf(float f) {
    unsigned u = __builtin_bit_cast(unsigned, f);
    u += 0x7fffu + ((u >> 16) & 1u);
    return (short)(u >> 16);
}

__device__ __forceinline__ float lrelu(float x) { return x > 0.0f ? x : 0.01f * x; }

// packed fp32x8 -> bf16x8 via v_cvt_pk_bf16_f32 (4 insts, not ~32)
__device__ __forceinline__ s16x8 cvt8(float4 lo, float4 hi) {
    union { s16x8 v; __hip_bfloat162 h[4]; } u;
    u.h[0] = __float22bfloat162_rn(make_float2(lo.x, lo.y));
    u.h[1] = __float22bfloat162_rn(make_float2(lo.z, lo.w));
    u.h[2] = __float22bfloat162_rn(make_float2(hi.x, hi.y));
    u.h[3] = __float22bfloat162_rn(make_float2(hi.z, hi.w));
    return u.v;
}

// ---- weight prep: WT[g][n][k] = bf16(W_g[k][n]), g in {src, tgt, edge} ----
__global__ void kprep(const float* __restrict__ Wsrc, const float* __restrict__ Wtgt,
                      const float* __restrict__ Wedge, u16* __restrict__ WT) {
    int i = blockIdx.x * 256 + threadIdx.x;
    if (i >= 3 * 16384) return;
    int g = i >> 14, nk = i & 16383, n = nk >> 7, k = nk & 127;
    const float* W = (g == 0) ? Wsrc : (g == 1) ? Wtgt : Wedge;
    WT[i] = (u16)f2bf(W[k * 128 + n]);
}

// ---- K1: R9 champion body (phase-overlap, ra dbuf) + packed cvt +
// coalesced ez epilogue via per-wave LDS bounce. ----
__global__ __launch_bounds__(256, 2) void k1(
    const float* __restrict__ recv, const float* __restrict__ send,
    const float* __restrict__ eattr, const int* __restrict__ sidx,
    const u16* __restrict__ WT, const float* __restrict__ attn,
    float* __restrict__ ez, float* __restrict__ denom)
{
    __shared__ u16 ldsA[128][136];
    __shared__ u16 ldsB[128][136];
    __shared__ float smEz[4][32][4];   // 2 KB, wave-private regions
    const int tid = threadIdx.x;
    const int lane = tid & 63, wv = tid >> 6;
    const int l15 = lane & 15, lg = (lane >> 4) & 3;
    const int blockRow = blockIdx.x * 128;

    const float* Xg[3] = {send, recv, eattr};

    f32x4 acc[2][8];
#pragma unroll
    for (int m = 0; m < 2; ++m)
#pragma unroll
        for (int n = 0; n < 8; ++n) acc[m][n] = (f32x4){0.f, 0.f, 0.f, 0.f};

    float4 ra[2][8][2];   // double-buffered in-flight A (128 VGPR)

    auto issueA = [&](int g, int buf) {
        const float* X = Xg[g];
#pragma unroll
        for (int q = 0; q < 8; ++q) {
            int idx = tid + 256 * q;
            int row = idx >> 4, gcol = (idx & 15) * 8;
            int ge = min(blockRow + row, E_EDGES - 1);
            const float* p = X + (size_t)ge * 128 + gcol;
            ra[buf][q][0] = *(const float4*)p;
            ra[buf][q][1] = *(const float4*)(p + 4);
        }
    };

    auto commitA = [&](int buf) {
#pragma unroll
        for (int q = 0; q < 8; ++q) {
            int idx = tid + 256 * q;
            *(s16x8*)&ldsA[idx >> 4][(idx & 15) * 8] = cvt8(ra[buf][q][0], ra[buf][q][1]);
        }
    };

    auto mfma_g = [&]() {
#pragma unroll
        for (int kk = 0; kk < 4; ++kk) {
            int k0 = kk * 32 + lg * 8;
            s16x8 a0 = *(const s16x8*)&ldsA[wv * 32 + l15][k0];
            s16x8 a1 = *(const s16x8*)&ldsA[wv * 32 + 16 + l15][k0];
#pragma unroll
            for (int n = 0; n < 8; ++n) {
                s16x8 b = *(const s16x8*)&ldsB[n * 16 + l15][k0];
                acc[0][n] = __builtin_amdgcn_mfma_f32_16x16x32_bf16(a0, b, acc[0][n], 0, 0, 0);
                acc[1][n] = __builtin_amdgcn_mfma_f32_16x16x32_bf16(a1, b, acc[1][n], 0, 0, 0);
            }
        }
    };

    issueA(0, 0);
#pragma unroll
    for (int g = 0; g < 3; ++g) {
        if (g) { mfma_g(); SCHED0(); }      // compute g-1 while A(g) streams in
        BAR();                               // all waves done reading LDS(g-1)
        s16x8 rb[8];
        {
            const u16* Bg = WT + g * 16384;
#pragma unroll
            for (int q = 0; q < 8; ++q) {
                int idx = tid + 256 * q;
                rb[q] = *(const s16x8*)(Bg + (idx >> 4) * 128 + (idx & 15) * 8);
            }
        }
        if (g < 2) issueA(g + 1, (g + 1) & 1);  // queue next-phase A before drain
        SCHED0();
        commitA(g & 1);
#pragma unroll
        for (int q = 0; q < 8; ++q) {
            int idx = tid + 256 * q;
            *(s16x8*)&ldsB[idx >> 4][(idx & 15) * 8] = rb[q];
        }
        SCHED0();
        WAITLGKM0();
        BAR();
    }
    mfma_g();                                // g = 2

    float av[8];
#pragma unroll
    for (int n = 0; n < 8; ++n) av[n] = attn[n * 16 + l15];

    // butterfly leaves the sum in ALL 16 lanes of each lg-group; park results
    // in wave-private LDS, then store coalesced.
#pragma unroll
    for (int m = 0; m < 2; ++m) {
#pragma unroll
        for (int h = 0; h < 4; ++h) {
            float part[4];
#pragma unroll
            for (int j = 0; j < 4; ++j)
                part[j] = lrelu(acc[m][2 * h][j]) * av[2 * h] +
                          lrelu(acc[m][2 * h + 1][j]) * av[2 * h + 1];
#pragma unroll
            for (int off = 1; off < 16; off <<= 1) {
#pragma unroll
                for (int j = 0; j < 4; ++j) part[j] += __shfl_xor(part[j], off, 64);
            }
            if (l15 == h) {
#pragma unroll
                for (int j = 0; j < 4; ++j)
                    smEz[wv][m * 16 + lg * 4 + j][h] = __expf(part[j]);
            }
        }
    }
    // wave-private region: in-order LDS per wave, compiler inserts lgkm wait
    {
        int row = lane >> 1, hp = (lane & 1) * 2;
        int r = blockRow + wv * 32 + row;
        float e0 = smEz[wv][row][hp];
        float e1 = smEz[wv][row][hp + 1];
        if (r < E_EDGES) {
            *(float2*)(ez + (size_t)r * 4 + hp) = make_float2(e0, e1);
            int s = sidx[r];
            atomicAdd(&denom[(size_t)s * 4 + hp], e0);
            atomicAdd(&denom[(size_t)s * 4 + hp + 1], e1);
        }
    }
}

// ---- K2: R9 proven structure (ldsA+ldsB, one sync), a = ez/denom fused ----
__global__ __launch_bounds__(256, 2) void k2(
    const float* __restrict__ recv, const int* __restrict__ ridx,
    const int* __restrict__ sidx, const u16* __restrict__ WTt,
    const float* __restrict__ ez, const float* __restrict__ denom,
    float* __restrict__ out0, float* __restrict__ out1)
{
    __shared__ u16 ldsA[128][136];
    __shared__ u16 ldsB[128][136];
    int tid = threadIdx.x;
    int lane = tid & 63, wv = tid >> 6;
    int l15 = lane & 15, lg = lane >> 4;
    int blockRow = blockIdx.x * 128;

    f32x4 acc[2][8];
#pragma unroll
    for (int m = 0; m < 2; ++m)
#pragma unroll
        for (int n = 0; n < 8; ++n) acc[m][n] = (f32x4){0.f, 0.f, 0.f, 0.f};

#pragma unroll
    for (int it = 0; it < 8; ++it) {
        int chunk = it * 256 + tid;
        int row = chunk >> 4, kc = (chunk & 15) << 3;
        int ge = min(blockRow + row, E_EDGES - 1);
        const float* p = recv + (size_t)ge * 128 + kc;
        float4 v0 = *(const float4*)p;
        float4 v1 = *(const float4*)(p + 4);
        *(s16x8*)&ldsA[row][kc] = cvt8(v0, v1);
    }
#pragma unroll
    for (int it = 0; it < 8; ++it) {
        int chunk = it * 256 + tid;
        int n = chunk >> 4, kc = (chunk & 15) << 3;
        *(s16x8*)&ldsB[n][kc] = *(const s16x8*)(WTt + n * 128 + kc);
    }
    __syncthreads();

#pragma unroll
    for (int kk = 0; kk < 4; ++kk) {
        int k0 = kk * 32 + lg * 8;
        s16x8 a0 = *(const s16x8*)&ldsA[wv * 32 + l15][k0];
        s16x8 a1 = *(const s16x8*)&ldsA[wv * 32 + 16 + l15][k0];
#pragma unroll
        for (int n = 0; n < 8; ++n) {
            s16x8 b = *(const s16x8*)&ldsB[n * 16 + l15][k0];
            acc[0][n] = __builtin_amdgcn_mfma_f32_16x16x32_bf16(a0, b, acc[0][n], 0, 0, 0);
            acc[1][n] = __builtin_amdgcn_mfma_f32_16x16x32_bf16(a1, b, acc[1][n], 0, 0, 0);
        }
    }

#pragma unroll
    for (int m = 0; m < 2; ++m) {
#pragma unroll
        for (int j = 0; j < 4; ++j) {
            int r = blockRow + wv * 32 + m * 16 + lg * 4 + j;
            if (r < E_EDGES) {
                int s = sidx[r];
                float4 ezv = *(const float4*)(ez + (size_t)r * 4);
                float4 dn = *(const float4*)(denom + (size_t)s * 4);
                float a0 = ezv.x / dn.x, a1 = ezv.y / dn.y;
                float a2 = ezv.z / dn.z, a3 = ezv.w / dn.w;
                float lo = 0.25f * (acc[m][0][j] * a0 + acc[m][2][j] * a1 +
                                    acc[m][4][j] * a2 + acc[m][6][j] * a3);
                float hi = 0.25f * (acc[m][1][j] * a0 + acc[m][3][j] * a1 +
                                    acc[m][5][j] * a2 + acc[m][7][j] * a3);
                out1[(size_t)r * 32 + l15] = lo;
                out1[(size_t)r * 32 + 16 + l15] = hi;
                int rv = ridx[r];
                atomicAdd(&out0[(size_t)rv * 32 + l15], lo);
                atomicAdd(&out0[(size_t)rv * 32 + 16 + l15], hi);
            }
        }
    }
}

extern "C" void kernel_launch(void* const* d_in, const int* in_sizes, int n_in,
                              void* d_out, int out_size, void* d_ws, size_t ws_size,
                              hipStream_t stream) {
    const float* recv  = (const float*)d_in[0];
    const float* send  = (const float*)d_in[1];
    const float* eattr = (const float*)d_in[2];
    const int*   sidx  = (const int*)d_in[3];
    const int*   ridx  = (const int*)d_in[4];
    const float* Wsrc  = (const float*)d_in[5];
    const float* Wtgt  = (const float*)d_in[6];
    const float* Wedge = (const float*)d_in[7];
    const float* attn  = (const float*)d_in[8];

    char* ws = (char*)d_ws;
    u16*   WT    = (u16*)ws;                         // 98304 B
    float* ez    = (float*)(ws + 131072);            // 8,000,000 B
    float* denom = (float*)(ws + 131072 + 8000000);  // 800,000 B

    float* out0 = (float*)d_out;                     // [N,32]
    float* out1 = out0 + (size_t)NN * 32;            // [E,32]

    hipMemsetAsync(denom, 0, (size_t)NN * 4 * sizeof(float), stream);
    hipMemsetAsync(out0, 0, (size_t)NN * 32 * sizeof(float), stream);

    kprep<<<192, 256, 0, stream>>>(Wsrc, Wtgt, Wedge, WT);

    int nb = (E_EDGES + 127) / 128;  // 3907
    k1<<<nb, 256, 0, stream>>>(recv, send, eattr, sidx, WT, attn, ez, denom);
    k2<<<nb, 256, 0, stream>>>(recv, ridx, sidx, WT + 16384, ez, denom, out0, out1);
}